// Round 12
// baseline (105.510 us; speedup 1.0000x reference)
//
#include <hip/hip_runtime.h>
#include <hip/hip_bf16.h>

#define B_ 16
#define SQ_ 2048
#define SK_ 2048
#define D_ 64
#define DV_ 64
#define INV_KEEP 1.1111111f  /* 1/(1-0.1) */
#define QSCALE 0.1803368801f /* 0.125 * log2(e): QK^T yields s*log2e; exp2 gives exp(s) */

typedef float f4 __attribute__((ext_vector_type(4)));
typedef __bf16 bf16x2 __attribute__((ext_vector_type(2)));
typedef __bf16 bf16x8 __attribute__((ext_vector_type(8)));
typedef short s16x4 __attribute__((ext_vector_type(4)));
typedef unsigned int u32;
typedef unsigned int u32x2 __attribute__((ext_vector_type(2)));
typedef unsigned int u32x4 __attribute__((ext_vector_type(4)));

// manual f32 -> bf16 RNE (prep kernels)
static __device__ __forceinline__ unsigned short bf16u(float f) {
    u32 u = __builtin_bit_cast(u32, f);
    u += 0x7fffu + ((u >> 16) & 1u);
    return (unsigned short)(u >> 16);
}
static __device__ __forceinline__ u32 pk2(float lo, float hi) {
    return (u32)bf16u(lo) | ((u32)bf16u(hi) << 16);
}
// hot-path pack: compiler emits v_cvt_pk_bf16_f32
static __device__ __forceinline__ u32 pkc(float lo, float hi) {
    bf16x2 t = {(__bf16)lo, (__bf16)hi};
    return __builtin_bit_cast(u32, t);
}

static __device__ __forceinline__ float fexp2(float x) {
#if __has_builtin(__builtin_amdgcn_exp2f)
    return __builtin_amdgcn_exp2f(x);
#else
    return exp2f(x);
#endif
}

static __device__ __forceinline__ void gload16(const void* g, void* l) {
    __builtin_amdgcn_global_load_lds(
        (const __attribute__((address_space(1))) unsigned int*)g,
        (__attribute__((address_space(3))) unsigned int*)l, 16, 0, 0);
}

// volatile-asm NON-TEMPORAL register load: pinned in program order AND
// bypasses L2 allocation (nt) so the 268 MB mask stream doesn't evict the
// K/V tiles every block re-reads.
template <int OFF>
static __device__ __forceinline__ f4 gload_f4_nt(const float* p) {
    f4 d;
    if constexpr (OFF == 0)
        asm volatile("global_load_dwordx4 %0, %1, off nt" : "=v"(d) : "v"(p));
    else
        asm volatile("global_load_dwordx4 %0, %1, off offset:%2 nt" : "=v"(d) : "v"(p), "i"(OFF));
    return d;
}

static __device__ __forceinline__ f4 mfma16(s16x4 a, s16x4 b, f4 c) {
#if __has_builtin(__builtin_amdgcn_mfma_f32_16x16x16bf16_1k)
    return __builtin_amdgcn_mfma_f32_16x16x16bf16_1k(a, b, c, 0, 0, 0);
#else
    f4 d;
    asm("v_mfma_f32_16x16x16_bf16 %0, %1, %2, %3" : "=v"(d) : "v"(a), "v"(b), "v"(c));
    return d;
#endif
}

// ---------------- fused prep: K and V -> bf16 lane-linear tile layouts ----------------
__global__ __launch_bounds__(256) void kv_retile(const float* __restrict__ K,
                                                 const float* __restrict__ V,
                                                 unsigned short* __restrict__ KbT,
                                                 unsigned short* __restrict__ VtT) {
    if (blockIdx.x < 1024) {
        int b = blockIdx.x >> 6, kt = blockIdx.x & 63;
        int p = threadIdx.x;
        int s = p >> 6, g = (p >> 4) & 3, c = p & 15;
        int t = s & 1, h = s >> 1;
        const float* src = K + ((size_t)(b * SK_ + kt * 32 + 16 * t + c)) * D_ + 32 * h + 8 * g;
        f4 a = *(const f4*)src;
        f4 b2 = *(const f4*)(src + 4);
        u32x4 w;
        w[0] = pk2(a.x, a.y); w[1] = pk2(a.z, a.w);
        w[2] = pk2(b2.x, b2.y); w[3] = pk2(b2.z, b2.w);
        *(u32x4*)(KbT + ((size_t)(b * 64 + kt)) * 2048 + (size_t)p * 8) = w;
    } else {
        __shared__ float vt[32][65];
        int id = blockIdx.x - 1024;
        int b = id >> 6, kt = id & 63;
        int tid = threadIdx.x;
#pragma unroll
        for (int e = 0; e < 2; ++e) {
            int f = tid * 2 + e;
            int row = f >> 4, c4 = (f & 15) * 4;
            *(f4*)&vt[row][c4] = *(const f4*)(V + ((size_t)(b * SK_ + kt * 32 + row)) * DV_ + c4);
        }
        __syncthreads();
        int vb = tid >> 6, g = (tid >> 4) & 3, c = tid & 15;
        int v = vb * 16 + c;
        u32x4 w;
        w[0] = pk2(vt[4 * g + 0][v], vt[4 * g + 1][v]);
        w[1] = pk2(vt[4 * g + 2][v], vt[4 * g + 3][v]);
        w[2] = pk2(vt[16 + 4 * g + 0][v], vt[16 + 4 * g + 1][v]);
        w[3] = pk2(vt[16 + 4 * g + 2][v], vt[16 + 4 * g + 3][v]);
        *(u32x4*)(VtT + ((size_t)(b * 64 + kt)) * 2048 + (size_t)tid * 8) = w;
    }
}

// ---------------- main fused attention kernel ----------------
// R9 structure, ONE change: mask loads are non-temporal (nt) so the stream
// doesn't allocate in L2 and K/V tiles stay L2-resident.
// Block = 4 waves = 4 consecutive q-strips, same (b, k-range). K/V in LDS
// (ring-4, depth-3, lane-linear conflict-free); mask in registers (ring-4),
// pair-issued at even tiles (256 B/row bursts). Derived waits: vmcnt(4)
// even tiles, vmcnt(8) odd. ONE barrier per tile. Swapped QK^T (16x16x32,
// log2e folded into Q), transposed PV (16x16x16) -> zero cross-lane ops.
// No max subtraction (scores ~N(0,1), f32-safe); 1/0.9 folded at the end.
template <int SPLIT>
__global__ __launch_bounds__(256) void attn_main(const float* __restrict__ Q,
                                                 const unsigned short* __restrict__ KbT,
                                                 const unsigned short* __restrict__ VtT,
                                                 const float* __restrict__ mask,
                                                 float* __restrict__ out,
                                                 float* __restrict__ accP,
                                                 float* __restrict__ lP) {
    constexpr int NT32 = SK_ / SPLIT / 32;     // 32-k tiles per wave
    constexpr int NB = 512 * SPLIT;
    __shared__ unsigned short sK[4][2048];     // 4 x 4KB
    __shared__ unsigned short sV[4][2048];     // 4 x 4KB

    int bswz = (blockIdx.x & 7) * (NB / 8) + (blockIdx.x >> 3);
    int wid  = threadIdx.x >> 6;
    int split = bswz & (SPLIT - 1);
    int strip = (bswz / SPLIT) * 4 + wid;
    int b  = strip >> 7;
    int q0 = (strip & 127) << 4;
    int kb = split * (SK_ / SPLIT);
    int lane = threadIdx.x & 63;
    int g = lane >> 4, c = lane & 15;

    const size_t tile0 = ((size_t)b * 64 + split * NT32) * 2048;
    const unsigned short* ksrc = KbT + tile0 + (size_t)threadIdx.x * 8;
    const unsigned short* vsrc = VtT + tile0 + (size_t)threadIdx.x * 8;
    const float* msrc = mask + ((size_t)(b * SQ_ + q0 + c)) * SK_ + kb + 4 * g;

    // Q fragments first; fully consumed (packed) before any volatile issue
    bf16x8 qf[2];
    {
        const float* qp = Q + ((size_t)(b * SQ_ + q0 + c)) * D_ + 8 * g;
#pragma unroll
        for (int h = 0; h < 2; ++h) {
            f4 a  = *(const f4*)(qp + h * 32);
            f4 bq = *(const f4*)(qp + h * 32 + 4);
            u32x4 wq;
            wq[0] = pk2(a.x * QSCALE, a.y * QSCALE);
            wq[1] = pk2(a.z * QSCALE, a.w * QSCALE);
            wq[2] = pk2(bq.x * QSCALE, bq.y * QSCALE);
            wq[3] = pk2(bq.z * QSCALE, bq.w * QSCALE);
            qf[h] = __builtin_bit_cast(bf16x8, wq);
        }
    }
    __builtin_amdgcn_sched_barrier(0);   // pin qf consumption before staging

    f4 mreg[4][2];   // mask ring, 4 slots (compile-time indices)

    auto kvload = [&](int dst, int srct) {
        gload16(ksrc + (size_t)srct * 2048, &sK[dst][wid * 512]);
        gload16(vsrc + (size_t)srct * 2048, &sV[dst][wid * 512]);
    };
    auto mload = [&](int dst, int srct) {
        const float* mp = msrc + (size_t)srct * 32;
        mreg[dst][0] = gload_f4_nt<0>(mp);
        mreg[dst][1] = gload_f4_nt<64>(mp);
    };

    // prologue queue (oldest->youngest): M0 M1 KV0 KV1 KV2  (10 ops)
    mload(0, 0);
    mload(1, 1);
    kvload(0, 0);
    kvload(1, 1);
    kvload(2, 2);

    f4 acc[4];
#pragma unroll
    for (int vb = 0; vb < 4; ++vb) acc[vb] = (f4){0.f, 0.f, 0.f, 0.f};
    f4 ls0 = (f4){0.f, 0.f, 0.f, 0.f}, ls1 = (f4){0.f, 0.f, 0.f, 0.f};

    const unsigned short* kbL = &sK[0][0] + lane * 8;
    const unsigned short* vbL = &sV[0][0] + lane * 8;

#pragma unroll 4
    for (int kt = 0; kt < NT32; ++kt) {
        // derived waits: even -> vmcnt(4) (completes M(kt..kt+1),KV(kt)),
        //                odd  -> vmcnt(8) (completes KV(kt))
        if ((kt & 1) == 0)
            asm volatile("s_waitcnt vmcnt(4)" ::: "memory");
        else
            asm volatile("s_waitcnt vmcnt(8)" ::: "memory");
        __builtin_amdgcn_s_barrier();
        __builtin_amdgcn_sched_barrier(0);

        // prefetch issues (overlap with this tile's compute):
        // KV(kt+3) -> slot (kt-1)&3, whose readers all passed this barrier
        kvload((kt + 3) & 3, (kt + 3 < NT32) ? kt + 3 : NT32 - 1);
        if ((kt & 1) == 0) {
            // mask pair for tiles kt+2, kt+3: 4 back-to-back dwordx4
            const int mt = (kt + 2 < NT32) ? kt + 2 : NT32 - 2;
            const float* mp = msrc + (size_t)mt * 32;
            mreg[(kt + 2) & 3][0] = gload_f4_nt<0>(mp);
            mreg[(kt + 2) & 3][1] = gload_f4_nt<64>(mp);
            mreg[(kt + 3) & 3][0] = gload_f4_nt<128>(mp);
            mreg[(kt + 3) & 3][1] = gload_f4_nt<192>(mp);
        }

        // ---- compute tile kt from slot bi ----
        const int bi = kt & 3;
        const unsigned short* kB = kbL + bi * 2048;
        const unsigned short* vB = vbL + bi * 2048;

        // QK^T: S^T rows k_local = 16t + 4g + r, col q = c (values = s*log2e)
        u32x4 ka0 = *(const u32x4*)(kB);            // t=0, d 0..31
        u32x4 ka1 = *(const u32x4*)(kB + 1024);     // t=0, d 32..63
        u32x4 kc0 = *(const u32x4*)(kB + 512);      // t=1, d 0..31
        u32x4 kc1 = *(const u32x4*)(kB + 1536);     // t=1, d 32..63
        f4 st0 = (f4){0.f, 0.f, 0.f, 0.f}, st1 = (f4){0.f, 0.f, 0.f, 0.f};
        st0 = __builtin_amdgcn_mfma_f32_16x16x32_bf16(__builtin_bit_cast(bf16x8, ka0), qf[0], st0, 0, 0, 0);
        st0 = __builtin_amdgcn_mfma_f32_16x16x32_bf16(__builtin_bit_cast(bf16x8, ka1), qf[1], st0, 0, 0, 0);
        st1 = __builtin_amdgcn_mfma_f32_16x16x32_bf16(__builtin_bit_cast(bf16x8, kc0), qf[0], st1, 0, 0, 0);
        st1 = __builtin_amdgcn_mfma_f32_16x16x32_bf16(__builtin_bit_cast(bf16x8, kc1), qf[1], st1, 0, 0, 0);

        // p = exp2(st) = exp(s); lane-local l; register-mask-gated dropout
        const f4 mk0 = mreg[bi][0], mk1 = mreg[bi][1];
        float pd0[4], pd1[4];
#pragma unroll
        for (int r = 0; r < 4; ++r) {
            float p0 = fexp2(st0[r]);
            ls0[r] += p0;
            pd0[r] = (mk0[r] > 0.1f) ? p0 : 0.f;
            float p1 = fexp2(st1[r]);
            ls1[r] += p1;
            pd1[r] = (mk1[r] > 0.1f) ? p1 : 0.f;
        }

        // PV (transposed): O^T[v][q] += V^T[v][k] * P^T[k][q]
        u32x2 pw0, pw1;
        pw0[0] = pkc(pd0[0], pd0[1]); pw0[1] = pkc(pd0[2], pd0[3]);
        pw1[0] = pkc(pd1[0], pd1[1]); pw1[1] = pkc(pd1[2], pd1[3]);
        s16x4 pb0 = __builtin_bit_cast(s16x4, pw0);
        s16x4 pb1 = __builtin_bit_cast(s16x4, pw1);
#pragma unroll
        for (int vb = 0; vb < 4; ++vb) {
            u32x4 vv = *(const u32x4*)(vB + vb * 512);
            u32x2 vlo, vhi;
            vlo[0] = vv[0]; vlo[1] = vv[1];
            vhi[0] = vv[2]; vhi[1] = vv[3];
            acc[vb] = mfma16(__builtin_bit_cast(s16x4, vlo), pb0, acc[vb]);
            acc[vb] = mfma16(__builtin_bit_cast(s16x4, vhi), pb1, acc[vb]);
        }
    }
    asm volatile("s_waitcnt vmcnt(0)" ::: "memory");   // drain dummies before exit

    // l reduce: lane-local partials -> per-column (q=c) total
    float lf = ls0[0] + ls0[1] + ls0[2] + ls0[3] + ls1[0] + ls1[1] + ls1[2] + ls1[3];
    lf += __shfl_xor(lf, 16);
    lf += __shfl_xor(lf, 32);   // lf = l(q=c) on every lane

    if constexpr (SPLIT == 1) {
        float li = INV_KEEP / lf;
        float* op = out + ((size_t)(b * SQ_ + q0 + c)) * DV_;
#pragma unroll
        for (int vb = 0; vb < 4; ++vb) {
            f4 o = acc[vb] * li;
            __builtin_nontemporal_store(o, (f4*)(op + 16 * vb + 4 * g));
        }
    } else {
        // lane-major partial: slot 4*vb+r = O^T[v=16vb+4g+r][q=c]
        float* ap = accP + (((size_t)strip * SPLIT + split) * 64 + lane) * 16;
#pragma unroll
        for (int vb = 0; vb < 4; ++vb)
            *(f4*)(ap + 4 * vb) = acc[vb];
        if (g == 0)
            lP[((size_t)strip * SPLIT + split) * 16 + c] = lf;
    }
}

// ---------------- combine kernel (SPLIT=2 path) ----------------
__global__ __launch_bounds__(256) void attn_combine2(const float* __restrict__ accP,
                                                     const float* __restrict__ lP,
                                                     float* __restrict__ out) {
    __shared__ float sacc[2 * 1280];   // 2 splits x 64 lanes x 16 slots, stride 20
    __shared__ float sl[32];
    int strip = blockIdx.x;
    int t = threadIdx.x;
    const float* src = accP + (size_t)strip * 2048;
#pragma unroll
    for (int s = 0; s < 2; ++s)
        *(f4*)&sacc[s * 1280 + (t >> 2) * 20 + (t & 3) * 4] = *(const f4*)(src + s * 1024 + t * 4);
    if (t < 32) sl[t] = lP[(size_t)strip * 32 + t];
    __syncthreads();

    int q = t >> 4, j = t & 15;        // output row q, f4-column j (v = 4j..4j+3)
    float L = sl[q] + sl[16 + q];
    float inv = INV_KEEP / L;
    // v = 4j+i -> lane = 16*(j&3)+q, slot = 4*(j>>2)+i
    int base = (16 * (j & 3) + q) * 20 + 4 * (j >> 2);
    f4 o = *(const f4*)&sacc[base] + *(const f4*)&sacc[1280 + base];
    o *= inv;
    int b  = strip >> 7;
    int q0 = (strip & 127) << 4;
    __builtin_nontemporal_store(o, (f4*)(out + ((size_t)(b * SQ_ + q0 + q)) * DV_ + 4 * j));
}

extern "C" void kernel_launch(void* const* d_in, const int* in_sizes, int n_in,
                              void* d_out, int out_size, void* d_ws, size_t ws_size,
                              hipStream_t stream) {
    const float* Q = (const float*)d_in[0];
    const float* K = (const float*)d_in[1];
    const float* V = (const float*)d_in[2];
    const float* M = (const float*)d_in[3];
    float* out = (float*)d_out;

    char* ws = (char*)d_ws;
    unsigned short* KbT  = (unsigned short*)ws;                               // 4 MB
    unsigned short* VtT  = (unsigned short*)(ws + (size_t)4 * 1024 * 1024);   // 4 MB
    float*          accP = (float*)         (ws + (size_t)8 * 1024 * 1024);   // 16 MB
    float*          lP   = (float*)         (ws + (size_t)24 * 1024 * 1024);  // 256 KB

    const size_t need_split = (size_t)24 * 1024 * 1024 + (size_t)2048 * 2 * 16 * 4;

    kv_retile<<<2048, 256, 0, stream>>>(K, V, KbT, VtT);
    if (ws_size >= need_split) {
        attn_main<2><<<1024, 256, 0, stream>>>(Q, KbT, VtT, M, out, accP, lP);
        attn_combine2<<<2048, 256, 0, stream>>>(accP, lP, out);
    } else {
        attn_main<1><<<512, 256, 0, stream>>>(Q, KbT, VtT, M, out, nullptr, nullptr);
    }
}

// Round 13
// 105.200 us; speedup vs baseline: 1.0029x; 1.0029x over previous
//
#include <hip/hip_runtime.h>
#include <hip/hip_bf16.h>

#define B_ 16
#define SQ_ 2048
#define SK_ 2048
#define D_ 64
#define DV_ 64
#define INV_KEEP 1.1111111f  /* 1/(1-0.1) */
#define QSCALE 0.1803368801f /* 0.125 * log2(e) */

typedef float f4 __attribute__((ext_vector_type(4)));
typedef __bf16 bf16x2 __attribute__((ext_vector_type(2)));
typedef __bf16 bf16x8 __attribute__((ext_vector_type(8)));
typedef short s16x4 __attribute__((ext_vector_type(4)));
typedef unsigned int u32;
typedef unsigned int u32x2 __attribute__((ext_vector_type(2)));
typedef unsigned int u32x4 __attribute__((ext_vector_type(4)));

static __device__ __forceinline__ unsigned short bf16u(float f) {
    u32 u = __builtin_bit_cast(u32, f);
    u += 0x7fffu + ((u >> 16) & 1u);
    return (unsigned short)(u >> 16);
}
static __device__ __forceinline__ u32 pk2(float lo, float hi) {
    return (u32)bf16u(lo) | ((u32)bf16u(hi) << 16);
}
static __device__ __forceinline__ u32 pkc(float lo, float hi) {
    bf16x2 t = {(__bf16)lo, (__bf16)hi};
    return __builtin_bit_cast(u32, t);
}
static __device__ __forceinline__ float fexp2(float x) {
#if __has_builtin(__builtin_amdgcn_exp2f)
    return __builtin_amdgcn_exp2f(x);
#else
    return exp2f(x);
#endif
}
static __device__ __forceinline__ void gload16(const void* g, void* l) {
    __builtin_amdgcn_global_load_lds(
        (const __attribute__((address_space(1))) unsigned int*)g,
        (__attribute__((address_space(3))) unsigned int*)l, 16, 0, 0);
}
template <int OFF>
static __device__ __forceinline__ f4 gload_f4(const float* p) {
    f4 d;
    if constexpr (OFF == 0)
        asm volatile("global_load_dwordx4 %0, %1, off" : "=v"(d) : "v"(p));
    else
        asm volatile("global_load_dwordx4 %0, %1, off offset:%2" : "=v"(d) : "v"(p), "i"(OFF));
    return d;
}
static __device__ __forceinline__ f4 mfma16(s16x4 a, s16x4 b, f4 c) {
#if __has_builtin(__builtin_amdgcn_mfma_f32_16x16x16bf16_1k)
    return __builtin_amdgcn_mfma_f32_16x16x16bf16_1k(a, b, c, 0, 0, 0);
#else
    f4 d;
    asm("v_mfma_f32_16x16x16_bf16 %0, %1, %2, %3" : "=v"(d) : "v"(a), "v"(b), "v"(c));
    return d;
#endif
}

// ---------------- fused prep: K and V -> bf16 lane-linear tile layouts ----------------
__global__ __launch_bounds__(256) void kv_retile(const float* __restrict__ K,
                                                 const float* __restrict__ V,
                                                 unsigned short* __restrict__ KbT,
                                                 unsigned short* __restrict__ VtT) {
    if (blockIdx.x < 1024) {
        int b = blockIdx.x >> 6, kt = blockIdx.x & 63;
        int p = threadIdx.x;
        int s = p >> 6, g = (p >> 4) & 3, c = p & 15;
        int t = s & 1, h = s >> 1;
        const float* src = K + ((size_t)(b * SK_ + kt * 32 + 16 * t + c)) * D_ + 32 * h + 8 * g;
        f4 a = *(const f4*)src;
        f4 b2 = *(const f4*)(src + 4);
        u32x4 w;
        w[0] = pk2(a.x, a.y); w[1] = pk2(a.z, a.w);
        w[2] = pk2(b2.x, b2.y); w[3] = pk2(b2.z, b2.w);
        *(u32x4*)(KbT + ((size_t)(b * 64 + kt)) * 2048 + (size_t)p * 8) = w;
    } else {
        __shared__ float vt[32][65];
        int id = blockIdx.x - 1024;
        int b = id >> 6, kt = id & 63;
        int tid = threadIdx.x;
#pragma unroll
        for (int e = 0; e < 2; ++e) {
            int f = tid * 2 + e;
            int row = f >> 4, c4 = (f & 15) * 4;
            *(f4*)&vt[row][c4] = *(const f4*)(V + ((size_t)(b * SK_ + kt * 32 + row)) * DV_ + c4);
        }
        __syncthreads();
        int vb = tid >> 6, g = (tid >> 4) & 3, c = tid & 15;
        int v = vb * 16 + c;
        u32x4 w;
        w[0] = pk2(vt[4 * g + 0][v], vt[4 * g + 1][v]);
        w[1] = pk2(vt[4 * g + 2][v], vt[4 * g + 3][v]);
        w[2] = pk2(vt[16 + 4 * g + 0][v], vt[16 + 4 * g + 1][v]);
        w[3] = pk2(vt[16 + 4 * g + 2][v], vt[16 + 4 * g + 3][v]);
        *(u32x4*)(VtT + ((size_t)(b * 64 + kt)) * 2048 + (size_t)tid * 8) = w;
    }
}

// ---------------- main fused attention kernel (thin-wave, high occupancy) ----------------
// VGPR-minimized for ~7 waves/SIMD (28 waves/CU): mask-stream BW scales with
// request concurrency (R5 compress @32 waves: 5.6 TB/s vs R9 @20: 3.5).
// Ring-2 KV in LDS (16 KB, 2 barriers/tile, uniform vmcnt(2)); ring-1 mask
// in regs (8 VGPR, 1-tile lead); scalar l (all 8 p's share q=c). Swapped
// QK^T (16x16x32, log2e in Q), transposed PV (16x16x16) -> zero cross-lane.
// Queue per tile (FIFO): [top: wait vmcnt(2) completes KV(kt)+M(kt)] ...
// mid: issue M(kt+1); after barrier2: issue KV(kt+2) into buf kt&1.
template <int SPLIT>
__global__ __launch_bounds__(256, 7) void attn_main(const float* __restrict__ Q,
                                                    const unsigned short* __restrict__ KbT,
                                                    const unsigned short* __restrict__ VtT,
                                                    const float* __restrict__ mask,
                                                    float* __restrict__ out,
                                                    float* __restrict__ accP,
                                                    float* __restrict__ lP) {
    constexpr int NT32 = SK_ / SPLIT / 32;     // tiles per wave (16 at SPLIT=4)
    constexpr int NB = 512 * SPLIT;
    __shared__ unsigned short sK[2][2048];     // 2 x 4KB
    __shared__ unsigned short sV[2][2048];     // 2 x 4KB

    int bswz = (blockIdx.x & 7) * (NB / 8) + (blockIdx.x >> 3);
    int wid  = threadIdx.x >> 6;
    int split = bswz & (SPLIT - 1);
    int strip = (bswz / SPLIT) * 4 + wid;
    int b  = strip >> 7;
    int q0 = (strip & 127) << 4;
    int kb = split * (SK_ / SPLIT);
    int lane = threadIdx.x & 63;
    int g = lane >> 4, c = lane & 15;

    const size_t tile0 = ((size_t)b * 64 + split * NT32) * 2048;
    const unsigned short* ksrc = KbT + tile0 + (size_t)threadIdx.x * 8;
    const unsigned short* vsrc = VtT + tile0 + (size_t)threadIdx.x * 8;
    const float* msrc = mask + ((size_t)(b * SQ_ + q0 + c)) * SK_ + kb + 4 * g;

    // Q fragments; consumed (packed) before staging begins
    bf16x8 qf[2];
    {
        const float* qp = Q + ((size_t)(b * SQ_ + q0 + c)) * D_ + 8 * g;
#pragma unroll
        for (int h = 0; h < 2; ++h) {
            f4 a  = *(const f4*)(qp + h * 32);
            f4 bq = *(const f4*)(qp + h * 32 + 4);
            u32x4 wq;
            wq[0] = pk2(a.x * QSCALE, a.y * QSCALE);
            wq[1] = pk2(a.z * QSCALE, a.w * QSCALE);
            wq[2] = pk2(bq.x * QSCALE, bq.y * QSCALE);
            wq[3] = pk2(bq.z * QSCALE, bq.w * QSCALE);
            qf[h] = __builtin_bit_cast(bf16x8, wq);
        }
    }
    __builtin_amdgcn_sched_barrier(0);

    auto kvload = [&](int dst, int srct) {
        gload16(ksrc + (size_t)srct * 2048, &sK[dst][wid * 512]);
        gload16(vsrc + (size_t)srct * 2048, &sV[dst][wid * 512]);
    };

    // ring-1 mask regs
    f4 mka, mkb;
    // prologue (oldest->youngest): M0(2) KV0(2) KV1(2)
    mka = gload_f4<0>(msrc);
    mkb = gload_f4<64>(msrc);
    kvload(0, 0);
    kvload(1, 1);

    f4 acc[4];
#pragma unroll
    for (int vb = 0; vb < 4; ++vb) acc[vb] = (f4){0.f, 0.f, 0.f, 0.f};
    float lf = 0.f;

    const unsigned short* kbL = &sK[0][0] + lane * 8;
    const unsigned short* vbL = &sV[0][0] + lane * 8;

#pragma unroll 4
    for (int kt = 0; kt < NT32; ++kt) {
        // completes exactly KV(kt)+M(kt); keeps KV(kt+1) in flight
        asm volatile("s_waitcnt vmcnt(2)" ::: "memory");
        __builtin_amdgcn_s_barrier();
        __builtin_amdgcn_sched_barrier(0);

        const int bi = kt & 1;
        const unsigned short* kB = kbL + bi * 2048;
        const unsigned short* vB = vbL + bi * 2048;

        // QK^T in two halves to limit live fragments
        f4 st0 = (f4){0.f, 0.f, 0.f, 0.f}, st1 = (f4){0.f, 0.f, 0.f, 0.f};
        {
            u32x4 ka = *(const u32x4*)(kB);         // t0, d0-31
            u32x4 kc = *(const u32x4*)(kB + 512);   // t1, d0-31
            st0 = __builtin_amdgcn_mfma_f32_16x16x32_bf16(__builtin_bit_cast(bf16x8, ka), qf[0], st0, 0, 0, 0);
            st1 = __builtin_amdgcn_mfma_f32_16x16x32_bf16(__builtin_bit_cast(bf16x8, kc), qf[0], st1, 0, 0, 0);
        }
        {
            u32x4 ka = *(const u32x4*)(kB + 1024);  // t0, d32-63
            u32x4 kc = *(const u32x4*)(kB + 1536);  // t1, d32-63
            st0 = __builtin_amdgcn_mfma_f32_16x16x32_bf16(__builtin_bit_cast(bf16x8, ka), qf[1], st0, 0, 0, 0);
            st1 = __builtin_amdgcn_mfma_f32_16x16x32_bf16(__builtin_bit_cast(bf16x8, kc), qf[1], st1, 0, 0, 0);
        }

        // p = exp2(st); scalar l (all 8 values share q=c); mask-gated dropout
        float pd0[4], pd1[4];
#pragma unroll
        for (int r = 0; r < 4; ++r) {
            float p0 = fexp2(st0[r]);
            lf += p0;
            pd0[r] = (mka[r] > 0.1f) ? p0 : 0.f;
            float p1 = fexp2(st1[r]);
            lf += p1;
            pd1[r] = (mkb[r] > 0.1f) ? p1 : 0.f;
        }

        // ring-1 mask reload for tile kt+1 (after consumption; before KV issue)
        {
            const float* mp = msrc + (size_t)((kt + 1 < NT32) ? kt + 1 : NT32 - 1) * 32;
            mka = gload_f4<0>(mp);
            mkb = gload_f4<64>(mp);
        }

        // PV (transposed): O^T[v][q] += V^T[v][k] * P^T[k][q]
        u32x2 pw0, pw1;
        pw0[0] = pkc(pd0[0], pd0[1]); pw0[1] = pkc(pd0[2], pd0[3]);
        pw1[0] = pkc(pd1[0], pd1[1]); pw1[1] = pkc(pd1[2], pd1[3]);
        s16x4 pb0 = __builtin_bit_cast(s16x4, pw0);
        s16x4 pb1 = __builtin_bit_cast(s16x4, pw1);
#pragma unroll
        for (int vb = 0; vb < 4; ++vb) {
            u32x4 vv = *(const u32x4*)(vB + vb * 512);
            u32x2 vlo, vhi;
            vlo[0] = vv[0]; vlo[1] = vv[1];
            vhi[0] = vv[2]; vhi[1] = vv[3];
            acc[vb] = mfma16(__builtin_bit_cast(s16x4, vlo), pb0, acc[vb]);
            acc[vb] = mfma16(__builtin_bit_cast(s16x4, vhi), pb1, acc[vb]);
        }

        __builtin_amdgcn_s_barrier();          // all waves done reading buf bi
        __builtin_amdgcn_sched_barrier(0);
        // restage KV(kt+2) into buf bi (readers all passed barrier2)
        kvload(bi, (kt + 2 < NT32) ? kt + 2 : NT32 - 1);
    }
    asm volatile("s_waitcnt vmcnt(0)" ::: "memory");   // drain dummies
    __builtin_amdgcn_sched_barrier(0);

    // l reduce: per-lane partial (8 k-rows of q=c) -> per-q total
    lf += __shfl_xor(lf, 16);
    lf += __shfl_xor(lf, 32);

    if constexpr (SPLIT == 1) {
        float li = INV_KEEP / lf;
        float* op = out + ((size_t)(b * SQ_ + q0 + c)) * DV_;
#pragma unroll
        for (int vb = 0; vb < 4; ++vb) {
            f4 o = acc[vb] * li;
            __builtin_nontemporal_store(o, (f4*)(op + 16 * vb + 4 * g));
        }
    } else {
        // lane-major partial: slot 4*vb+r = O^T[v=16vb+4g+r][q=c]
        float* ap = accP + (((size_t)strip * SPLIT + split) * 64 + lane) * 16;
#pragma unroll
        for (int vb = 0; vb < 4; ++vb)
            *(f4*)(ap + 4 * vb) = acc[vb];
        if (g == 0)
            lP[((size_t)strip * SPLIT + split) * 16 + c] = lf;
    }
}

// ---------------- combine kernel (SPLIT=4 path) ----------------
__global__ __launch_bounds__(256) void attn_combine4(const float* __restrict__ accP,
                                                     const float* __restrict__ lP,
                                                     float* __restrict__ out) {
    __shared__ float sacc[4 * 1280];   // 4 splits x 64 lanes x 16 slots, stride 20
    __shared__ float sl[64];
    int strip = blockIdx.x;
    int t = threadIdx.x;
    const float* src = accP + (size_t)strip * 4096;
#pragma unroll
    for (int s = 0; s < 4; ++s)
        *(f4*)&sacc[s * 1280 + (t >> 2) * 20 + (t & 3) * 4] = *(const f4*)(src + s * 1024 + t * 4);
    if (t < 64) sl[t] = lP[(size_t)strip * 64 + t];
    __syncthreads();

    int q = t >> 4, j = t & 15;        // output row q, f4-column j (v = 4j..4j+3)
    float L = sl[q] + sl[16 + q] + sl[32 + q] + sl[48 + q];
    float inv = INV_KEEP / L;
    int base = (16 * (j & 3) + q) * 20 + 4 * (j >> 2);
    f4 o = (f4){0.f, 0.f, 0.f, 0.f};
#pragma unroll
    for (int s = 0; s < 4; ++s)
        o += *(const f4*)&sacc[s * 1280 + base];
    o *= inv;
    int b  = strip >> 7;
    int q0 = (strip & 127) << 4;
    __builtin_nontemporal_store(o, (f4*)(out + ((size_t)(b * SQ_ + q0 + q)) * DV_ + 4 * j));
}

extern "C" void kernel_launch(void* const* d_in, const int* in_sizes, int n_in,
                              void* d_out, int out_size, void* d_ws, size_t ws_size,
                              hipStream_t stream) {
    const float* Q = (const float*)d_in[0];
    const float* K = (const float*)d_in[1];
    const float* V = (const float*)d_in[2];
    const float* M = (const float*)d_in[3];
    float* out = (float*)d_out;

    char* ws = (char*)d_ws;
    unsigned short* KbT  = (unsigned short*)ws;                               // 4 MB
    unsigned short* VtT  = (unsigned short*)(ws + (size_t)4 * 1024 * 1024);   // 4 MB
    float*          accP = (float*)         (ws + (size_t)8 * 1024 * 1024);   // 32 MB
    float*          lP   = (float*)         (ws + (size_t)40 * 1024 * 1024);  // 512 KB

    const size_t need_split = (size_t)40 * 1024 * 1024 + (size_t)2048 * 4 * 16 * 4;

    kv_retile<<<2048, 256, 0, stream>>>(K, V, KbT, VtT);
    if (ws_size >= need_split) {
        attn_main<4><<<2048, 256, 0, stream>>>(Q, KbT, VtT, M, out, accP, lP);
        attn_combine4<<<2048, 256, 0, stream>>>(accP, lP, out);
    } else {
        attn_main<1><<<512, 256, 0, stream>>>(Q, KbT, VtT, M, out, nullptr, nullptr);
    }
}

// Round 14
// 90.340 us; speedup vs baseline: 1.1679x; 1.1645x over previous
//
#include <hip/hip_runtime.h>
#include <hip/hip_bf16.h>

#define B_ 16
#define SQ_ 2048
#define SK_ 2048
#define D_ 64
#define DV_ 64
#define INV_KEEP 1.1111111f  /* 1/(1-0.1) */
#define QSCALE 0.1803368801f /* 0.125 * log2(e): QK^T yields s*log2e; exp2 gives exp(s) */

typedef float f4 __attribute__((ext_vector_type(4)));
typedef __bf16 bf16x2 __attribute__((ext_vector_type(2)));
typedef __bf16 bf16x8 __attribute__((ext_vector_type(8)));
typedef short s16x4 __attribute__((ext_vector_type(4)));
typedef unsigned int u32;
typedef unsigned int u32x2 __attribute__((ext_vector_type(2)));
typedef unsigned int u32x4 __attribute__((ext_vector_type(4)));

static __device__ __forceinline__ unsigned short bf16u(float f) {
    u32 u = __builtin_bit_cast(u32, f);
    u += 0x7fffu + ((u >> 16) & 1u);
    return (unsigned short)(u >> 16);
}
static __device__ __forceinline__ u32 pk2(float lo, float hi) {
    return (u32)bf16u(lo) | ((u32)bf16u(hi) << 16);
}
static __device__ __forceinline__ u32 pkc(float lo, float hi) {
    bf16x2 t = {(__bf16)lo, (__bf16)hi};
    return __builtin_bit_cast(u32, t);
}
static __device__ __forceinline__ float fexp2(float x) {
#if __has_builtin(__builtin_amdgcn_exp2f)
    return __builtin_amdgcn_exp2f(x);
#else
    return exp2f(x);
#endif
}
static __device__ __forceinline__ void gload16(const void* g, void* l) {
    __builtin_amdgcn_global_load_lds(
        (const __attribute__((address_space(1))) unsigned int*)g,
        (__attribute__((address_space(3))) unsigned int*)l, 16, 0, 0);
}
template <int OFF>
static __device__ __forceinline__ f4 gload_f4(const float* p) {
    f4 d;
    if constexpr (OFF == 0)
        asm volatile("global_load_dwordx4 %0, %1, off" : "=v"(d) : "v"(p));
    else
        asm volatile("global_load_dwordx4 %0, %1, off offset:%2" : "=v"(d) : "v"(p), "i"(OFF));
    return d;
}
static __device__ __forceinline__ f4 mfma16(s16x4 a, s16x4 b, f4 c) {
#if __has_builtin(__builtin_amdgcn_mfma_f32_16x16x16bf16_1k)
    return __builtin_amdgcn_mfma_f32_16x16x16bf16_1k(a, b, c, 0, 0, 0);
#else
    f4 d;
    asm("v_mfma_f32_16x16x16_bf16 %0, %1, %2, %3" : "=v"(d) : "v"(a), "v"(b), "v"(c));
    return d;
#endif
}

// ---------------- fused prep: K and V -> bf16 lane-linear tile layouts ----------------
__global__ __launch_bounds__(256) void kv_retile(const float* __restrict__ K,
                                                 const float* __restrict__ V,
                                                 unsigned short* __restrict__ KbT,
                                                 unsigned short* __restrict__ VtT) {
    if (blockIdx.x < 1024) {
        int b = blockIdx.x >> 6, kt = blockIdx.x & 63;
        int p = threadIdx.x;
        int s = p >> 6, g = (p >> 4) & 3, c = p & 15;
        int t = s & 1, h = s >> 1;
        const float* src = K + ((size_t)(b * SK_ + kt * 32 + 16 * t + c)) * D_ + 32 * h + 8 * g;
        f4 a = *(const f4*)src;
        f4 b2 = *(const f4*)(src + 4);
        u32x4 w;
        w[0] = pk2(a.x, a.y); w[1] = pk2(a.z, a.w);
        w[2] = pk2(b2.x, b2.y); w[3] = pk2(b2.z, b2.w);
        *(u32x4*)(KbT + ((size_t)(b * 64 + kt)) * 2048 + (size_t)p * 8) = w;
    } else {
        __shared__ float vt[32][65];
        int id = blockIdx.x - 1024;
        int b = id >> 6, kt = id & 63;
        int tid = threadIdx.x;
#pragma unroll
        for (int e = 0; e < 2; ++e) {
            int f = tid * 2 + e;
            int row = f >> 4, c4 = (f & 15) * 4;
            *(f4*)&vt[row][c4] = *(const f4*)(V + ((size_t)(b * SK_ + kt * 32 + row)) * DV_ + c4);
        }
        __syncthreads();
        int vb = tid >> 6, g = (tid >> 4) & 3, c = tid & 15;
        int v = vb * 16 + c;
        u32x4 w;
        w[0] = pk2(vt[4 * g + 0][v], vt[4 * g + 1][v]);
        w[1] = pk2(vt[4 * g + 2][v], vt[4 * g + 3][v]);
        w[2] = pk2(vt[16 + 4 * g + 0][v], vt[16 + 4 * g + 1][v]);
        w[3] = pk2(vt[16 + 4 * g + 2][v], vt[16 + 4 * g + 3][v]);
        *(u32x4*)(VtT + ((size_t)(b * 64 + kt)) * 2048 + (size_t)tid * 8) = w;
    }
}

// ---------------- main fused attention kernel (64-k supertiles) ----------------
// R9 structure with halved per-byte overhead: 64-k supertiles (2x 4KB K tiles
// + 2x 4KB V tiles per step), ring-2 LDS (32 KB), ONE uniform vmcnt(8) wait
// per step (FIFO: prologue KV0,M0,KV1,M1 = 16 outstanding; each iter
// completes 8, issues 8), mask 256 B/row in one 4-load group, MFMAs
// clustered (8x QK, 16x PV) under s_setprio(1) (T5: phase-split wave
// arbitration). Swapped QK^T (16x16x32, log2e folded into Q), transposed PV
// (16x16x16, B-op = QK^T C-layout) -> zero cross-lane ops. No max
// subtraction (scores ~N(0,1), f32-safe); l lane-local; 1/0.9 at the end.
template <int SPLIT>
__global__ __launch_bounds__(256) void attn_main(const float* __restrict__ Q,
                                                 const unsigned short* __restrict__ KbT,
                                                 const unsigned short* __restrict__ VtT,
                                                 const float* __restrict__ mask,
                                                 float* __restrict__ out,
                                                 float* __restrict__ accP,
                                                 float* __restrict__ lP) {
    constexpr int NT64 = SK_ / SPLIT / 64;     // 64-k supertiles per wave (16 at SPLIT=2)
    constexpr int NB = 512 * SPLIT;
    __shared__ unsigned short sK[2][4096];     // 2 x 8KB
    __shared__ unsigned short sV[2][4096];     // 2 x 8KB

    int bswz = (blockIdx.x & 7) * (NB / 8) + (blockIdx.x >> 3);
    int wid  = threadIdx.x >> 6;
    int split = bswz & (SPLIT - 1);
    int strip = (bswz / SPLIT) * 4 + wid;
    int b  = strip >> 7;
    int q0 = (strip & 127) << 4;
    int kb = split * (SK_ / SPLIT);
    int lane = threadIdx.x & 63;
    int g = lane >> 4, c = lane & 15;

    const size_t tile0 = ((size_t)b * 64 + split * (SK_ / SPLIT / 32)) * 2048;
    const unsigned short* ksrc = KbT + tile0 + (size_t)threadIdx.x * 8;
    const unsigned short* vsrc = VtT + tile0 + (size_t)threadIdx.x * 8;
    const float* msrc = mask + ((size_t)(b * SQ_ + q0 + c)) * SK_ + kb + 4 * g;

    // Q fragments; fully consumed (packed) before any staging
    bf16x8 qf[2];
    {
        const float* qp = Q + ((size_t)(b * SQ_ + q0 + c)) * D_ + 8 * g;
#pragma unroll
        for (int h = 0; h < 2; ++h) {
            f4 a  = *(const f4*)(qp + h * 32);
            f4 bq = *(const f4*)(qp + h * 32 + 4);
            u32x4 wq;
            wq[0] = pk2(a.x * QSCALE, a.y * QSCALE);
            wq[1] = pk2(a.z * QSCALE, a.w * QSCALE);
            wq[2] = pk2(bq.x * QSCALE, bq.y * QSCALE);
            wq[3] = pk2(bq.z * QSCALE, bq.w * QSCALE);
            qf[h] = __builtin_bit_cast(bf16x8, wq);
        }
    }
    __builtin_amdgcn_sched_barrier(0);

    f4 mr[2][4];   // mask ring-2; [buf][j]: j = 2*dhalf? no: j = (khalf<<1)+t, 64 B apart

    auto kvload = [&](int buf, int st) {
        const unsigned short* kp = ksrc + (size_t)st * 4096;
        gload16(kp,        &sK[buf][wid * 512]);
        gload16(kp + 2048, &sK[buf][2048 + wid * 512]);
        const unsigned short* vp = vsrc + (size_t)st * 4096;
        gload16(vp,        &sV[buf][wid * 512]);
        gload16(vp + 2048, &sV[buf][2048 + wid * 512]);
    };
    auto mload = [&](int buf, int st) {
        const float* mp = msrc + (size_t)st * 64;
        mr[buf][0] = gload_f4<0>(mp);     // k = st*64 + 4g + r
        mr[buf][1] = gload_f4<64>(mp);    // k = st*64 + 16 + 4g + r
        mr[buf][2] = gload_f4<128>(mp);   // k = st*64 + 32 + 4g + r
        mr[buf][3] = gload_f4<192>(mp);   // k = st*64 + 48 + 4g + r
    };

    // prologue (oldest->youngest): KV0(4) M0(4) KV1(4) M1(4) = 16 outstanding
    kvload(0, 0); mload(0, 0);
    kvload(1, 1); mload(1, 1);

    f4 acc[4];
#pragma unroll
    for (int vb = 0; vb < 4; ++vb) acc[vb] = (f4){0.f, 0.f, 0.f, 0.f};
    f4 ls0 = (f4){0.f, 0.f, 0.f, 0.f}, ls1 = (f4){0.f, 0.f, 0.f, 0.f};

    const unsigned short* kbL = &sK[0][0] + lane * 8;
    const unsigned short* vbL = &sV[0][0] + lane * 8;

#pragma unroll 4
    for (int st = 0; st < NT64; ++st) {
        // completes exactly KV(st)+M(st); keeps KV(st+1)+M(st+1) in flight
        asm volatile("s_waitcnt vmcnt(8)" ::: "memory");
        __builtin_amdgcn_s_barrier();
        __builtin_amdgcn_sched_barrier(0);

        const int buf = st & 1;
        const unsigned short* kB = kbL + buf * 4096;
        const unsigned short* vB = vbL + buf * 4096;

        // QK^T: 4 score tiles stt[j], j = (khalf<<1)+t; rows k_local = j*16+4g+r, col q = c
        f4 stt[4];
        __builtin_amdgcn_s_setprio(1);
#pragma unroll
        for (int h = 0; h < 2; ++h) {     // h = 32-k half (sub-tile A/B)
            u32x4 k0 = *(const u32x4*)(kB + h * 2048);           // t=0, d 0..31
            u32x4 k1 = *(const u32x4*)(kB + h * 2048 + 512);     // t=1, d 0..31
            u32x4 k2 = *(const u32x4*)(kB + h * 2048 + 1024);    // t=0, d 32..63
            u32x4 k3 = *(const u32x4*)(kB + h * 2048 + 1536);    // t=1, d 32..63
            f4 s0 = (f4){0.f, 0.f, 0.f, 0.f}, s1 = (f4){0.f, 0.f, 0.f, 0.f};
            s0 = __builtin_amdgcn_mfma_f32_16x16x32_bf16(__builtin_bit_cast(bf16x8, k0), qf[0], s0, 0, 0, 0);
            s0 = __builtin_amdgcn_mfma_f32_16x16x32_bf16(__builtin_bit_cast(bf16x8, k2), qf[1], s0, 0, 0, 0);
            s1 = __builtin_amdgcn_mfma_f32_16x16x32_bf16(__builtin_bit_cast(bf16x8, k1), qf[0], s1, 0, 0, 0);
            s1 = __builtin_amdgcn_mfma_f32_16x16x32_bf16(__builtin_bit_cast(bf16x8, k3), qf[1], s1, 0, 0, 0);
            stt[h * 2]     = s0;
            stt[h * 2 + 1] = s1;
        }
        __builtin_amdgcn_s_setprio(0);

        // p = exp2(stt) = exp(s); lane-local l; register-mask-gated dropout
        float pd[4][4];
#pragma unroll
        for (int j = 0; j < 4; ++j) {
            const f4 mk = mr[buf][j];
#pragma unroll
            for (int r = 0; r < 4; ++r) {
                float p = fexp2(stt[j][r]);
                if (j & 1) ls1[r] += p; else ls0[r] += p;
                pd[j][r] = (mk[r] > 0.1f) ? p : 0.f;
            }
        }

        // PV (transposed): O^T[v][q] += V^T[v][k] * P^T[k][q], per 32-k half
        __builtin_amdgcn_s_setprio(1);
#pragma unroll
        for (int h = 0; h < 2; ++h) {
            u32x2 pw0, pw1;
            pw0[0] = pkc(pd[h * 2][0], pd[h * 2][1]);
            pw0[1] = pkc(pd[h * 2][2], pd[h * 2][3]);
            pw1[0] = pkc(pd[h * 2 + 1][0], pd[h * 2 + 1][1]);
            pw1[1] = pkc(pd[h * 2 + 1][2], pd[h * 2 + 1][3]);
            s16x4 pb0 = __builtin_bit_cast(s16x4, pw0);
            s16x4 pb1 = __builtin_bit_cast(s16x4, pw1);
#pragma unroll
            for (int vb = 0; vb < 4; ++vb) {
                u32x4 vv = *(const u32x4*)(vB + h * 2048 + vb * 512);
                u32x2 vlo, vhi;
                vlo[0] = vv[0]; vlo[1] = vv[1];
                vhi[0] = vv[2]; vhi[1] = vv[3];
                acc[vb] = mfma16(__builtin_bit_cast(s16x4, vlo), pb0, acc[vb]);
                acc[vb] = mfma16(__builtin_bit_cast(s16x4, vhi), pb1, acc[vb]);
            }
        }
        __builtin_amdgcn_s_setprio(0);

        __builtin_amdgcn_s_barrier();   // all waves done reading buf
        __builtin_amdgcn_sched_barrier(0);
        // restage buf with supertile st+2 (clamped dummy at tail keeps counts uniform)
        {
            const int nt = (st + 2 < NT64) ? st + 2 : NT64 - 1;
            kvload(buf, nt);
            mload(buf, nt);
        }
    }
    asm volatile("s_waitcnt vmcnt(0)" ::: "memory");   // drain dummies
    __builtin_amdgcn_sched_barrier(0);

    // l reduce: lane-local partials -> per-column (q=c) total
    float lf = ls0[0] + ls0[1] + ls0[2] + ls0[3] + ls1[0] + ls1[1] + ls1[2] + ls1[3];
    lf += __shfl_xor(lf, 16);
    lf += __shfl_xor(lf, 32);   // lf = l(q=c) on every lane

    if constexpr (SPLIT == 1) {
        float li = INV_KEEP / lf;
        float* op = out + ((size_t)(b * SQ_ + q0 + c)) * DV_;
#pragma unroll
        for (int vb = 0; vb < 4; ++vb) {
            f4 o = acc[vb] * li;
            __builtin_nontemporal_store(o, (f4*)(op + 16 * vb + 4 * g));
        }
    } else {
        // lane-major partial: slot 4*vb+r = O^T[v=16vb+4g+r][q=c]
        float* ap = accP + (((size_t)strip * SPLIT + split) * 64 + lane) * 16;
#pragma unroll
        for (int vb = 0; vb < 4; ++vb)
            *(f4*)(ap + 4 * vb) = acc[vb];
        if (g == 0)
            lP[((size_t)strip * SPLIT + split) * 16 + c] = lf;
    }
}

// ---------------- combine kernel (SPLIT=2 path) ----------------
__global__ __launch_bounds__(256) void attn_combine2(const float* __restrict__ accP,
                                                     const float* __restrict__ lP,
                                                     float* __restrict__ out) {
    __shared__ float sacc[2 * 1280];   // 2 splits x 64 lanes x 16 slots, stride 20
    __shared__ float sl[32];
    int strip = blockIdx.x;
    int t = threadIdx.x;
    const float* src = accP + (size_t)strip * 2048;
#pragma unroll
    for (int s = 0; s < 2; ++s)
        *(f4*)&sacc[s * 1280 + (t >> 2) * 20 + (t & 3) * 4] = *(const f4*)(src + s * 1024 + t * 4);
    if (t < 32) sl[t] = lP[(size_t)strip * 32 + t];
    __syncthreads();

    int q = t >> 4, j = t & 15;        // output row q, f4-column j (v = 4j..4j+3)
    float L = sl[q] + sl[16 + q];
    float inv = INV_KEEP / L;
    // v = 4j+i -> lane = 16*(j&3)+q, slot = 4*(j>>2)+i
    int base = (16 * (j & 3) + q) * 20 + 4 * (j >> 2);
    f4 o = *(const f4*)&sacc[base] + *(const f4*)&sacc[1280 + base];
    o *= inv;
    int b  = strip >> 7;
    int q0 = (strip & 127) << 4;
    __builtin_nontemporal_store(o, (f4*)(out + ((size_t)(b * SQ_ + q0 + q)) * DV_ + 4 * j));
}

extern "C" void kernel_launch(void* const* d_in, const int* in_sizes, int n_in,
                              void* d_out, int out_size, void* d_ws, size_t ws_size,
                              hipStream_t stream) {
    const float* Q = (const float*)d_in[0];
    const float* K = (const float*)d_in[1];
    const float* V = (const float*)d_in[2];
    const float* M = (const float*)d_in[3];
    float* out = (float*)d_out;

    char* ws = (char*)d_ws;
    unsigned short* KbT  = (unsigned short*)ws;                               // 4 MB
    unsigned short* VtT  = (unsigned short*)(ws + (size_t)4 * 1024 * 1024);   // 4 MB
    float*          accP = (float*)         (ws + (size_t)8 * 1024 * 1024);   // 16 MB
    float*          lP   = (float*)         (ws + (size_t)24 * 1024 * 1024);  // 256 KB

    const size_t need_split = (size_t)24 * 1024 * 1024 + (size_t)2048 * 2 * 16 * 4;

    kv_retile<<<2048, 256, 0, stream>>>(K, V, KbT, VtT);
    if (ws_size >= need_split) {
        attn_main<2><<<1024, 256, 0, stream>>>(Q, KbT, VtT, M, out, accP, lP);
        attn_combine2<<<2048, 256, 0, stream>>>(accP, lP, out);
    } else {
        attn_main<1><<<512, 256, 0, stream>>>(Q, KbT, VtT, M, out, nullptr, nullptr);
    }
}